// Round 1
// baseline (151.637 us; speedup 1.0000x reference)
//
#include <hip/hip_runtime.h>
#include <hip/hip_bf16.h>
#include <stdint.h>

#define B_DIM 32768
#define IN_DIM 512
#define OUT_DIM 512

typedef __bf16 bf16;
typedef bf16 bf16x8 __attribute__((ext_vector_type(8)));
typedef float f32x4 __attribute__((ext_vector_type(4)));

// ---- quantize: xi = trunc_to_int(v * 2^sf); keep top-4 significant bits of |xi|; restore sign ----
__device__ __forceinline__ float quant_trunc(float v, float scale) {
    int xi = (int)(v * scale);               // C cast truncates toward zero, matches astype(int32)
    int a  = xi < 0 ? -xi : xi;
    int bl = a ? (32 - __builtin_clz((unsigned)a)) : 0;
    int sh = bl > 4 ? bl - 4 : 0;
    int t  = (a >> sh) << sh;
    return (float)(xi < 0 ? -t : t);         // <=4 significant bits: exact in bf16
}

__global__ void quant_kernel(const float* __restrict__ in, bf16* __restrict__ out,
                             int n4, const int* __restrict__ sf) {
    int i = blockIdx.x * blockDim.x + threadIdx.x;
    if (i >= n4) return;
    float scale = (float)(1 << *sf);
    float4 v = ((const float4*)in)[i];
    union { bf16 h[4]; uint2 u; } cv;
    cv.h[0] = (bf16)quant_trunc(v.x, scale);
    cv.h[1] = (bf16)quant_trunc(v.y, scale);
    cv.h[2] = (bf16)quant_trunc(v.z, scale);
    cv.h[3] = (bf16)quant_trunc(v.w, scale);
    ((uint2*)out)[i] = cv.u;
}

// ---- bf16 GEMM: C[m,n] = sum_k A[m,k]*W[n,k], * 2^-(asf+wsf), + bias[n] ----
// A: [32768,512] bf16 row-major, W: [512,512] bf16 row-major (B^T form), C: fp32.
// 128x128 block tile, BK=64, 4 waves in 2x2, each wave 64x64 via 4x4 of 16x16x32 MFMA.
__global__ __launch_bounds__(256)
void gemm_bt(const bf16* __restrict__ A, const bf16* __restrict__ W,
             const float* __restrict__ bias, float* __restrict__ C,
             const int* __restrict__ wsf, const int* __restrict__ asf) {
    __shared__ bf16 As[128 * 64];
    __shared__ bf16 Bs[128 * 64];

    const int t    = threadIdx.x;
    const int w    = t >> 6;          // wave 0..3
    const int lane = t & 63;
    const int bm   = blockIdx.x >> 2; // 256 M-tiles
    const int bn   = blockIdx.x & 3;  // 4 N-tiles
    const int row0 = bm * 128;
    const int col0 = bn * 128;
    const int wm   = (w & 1) * 64;    // wave offset in M
    const int wn   = (w >> 1) * 64;   // wave offset in N

    // staging geometry: each thread loads 16B/issue, 8 threads cover one 64-elem row
    const int ldr = t >> 3;           // row within 32-row chunk
    const int ldc = (t & 7) * 8;      // element column

    const bf16* Abase = A + (size_t)row0 * IN_DIM;
    const bf16* Wbase = W + (size_t)col0 * IN_DIM;

    f32x4 acc[4][4];
    for (int mt = 0; mt < 4; ++mt)
        for (int nt = 0; nt < 4; ++nt)
            acc[mt][nt] = 0.0f;

    for (int k0 = 0; k0 < IN_DIM; k0 += 64) {
        // ---- global -> LDS staging (async, 16B/lane). LDS dst = wave-uniform base + lane*16.
        #pragma unroll
        for (int i = 0; i < 4; ++i) {
            const bf16* ga = Abase + (size_t)(i * 32 + ldr) * IN_DIM + k0 + ldc;
            bf16*       la = As + i * 2048 + w * 512;   // elements: (i*32 + w*8)*64
            __builtin_amdgcn_global_load_lds((const __attribute__((address_space(1))) void*)ga,
                                             (__attribute__((address_space(3))) void*)la, 16, 0, 0);
            const bf16* gb = Wbase + (size_t)(i * 32 + ldr) * IN_DIM + k0 + ldc;
            bf16*       lb = Bs + i * 2048 + w * 512;
            __builtin_amdgcn_global_load_lds((const __attribute__((address_space(1))) void*)gb,
                                             (__attribute__((address_space(3))) void*)lb, 16, 0, 0);
        }
        __syncthreads();   // compiler drains vmcnt before s_barrier

        // ---- compute: 2 k-steps of 32
        #pragma unroll
        for (int ks = 0; ks < 2; ++ks) {
            const int kcol = ks * 32 + (lane >> 4) * 8;
            const int arow = wm + (lane & 15);
            const int brow = wn + (lane & 15);
            bf16x8 af[4], bf[4];
            #pragma unroll
            for (int mt = 0; mt < 4; ++mt)
                af[mt] = *(const bf16x8*)(As + (arow + mt * 16) * 64 + kcol);
            #pragma unroll
            for (int nt = 0; nt < 4; ++nt)
                bf[nt] = *(const bf16x8*)(Bs + (brow + nt * 16) * 64 + kcol);
            #pragma unroll
            for (int mt = 0; mt < 4; ++mt)
                #pragma unroll
                for (int nt = 0; nt < 4; ++nt)
                    acc[mt][nt] = __builtin_amdgcn_mfma_f32_16x16x32_bf16(af[mt], bf[nt], acc[mt][nt], 0, 0, 0);
        }
        __syncthreads();
    }

    // ---- epilogue: C/D layout col=lane&15, row=(lane>>4)*4+reg
    const float oscale = ldexpf(1.0f, -(*wsf + *asf));
    const int cl = lane & 15;
    const int rg = (lane >> 4) * 4;
    #pragma unroll
    for (int nt = 0; nt < 4; ++nt) {
        const int col = col0 + wn + nt * 16 + cl;
        const float bv = bias[col];
        #pragma unroll
        for (int mt = 0; mt < 4; ++mt) {
            f32x4 a = acc[mt][nt];
            #pragma unroll
            for (int r = 0; r < 4; ++r) {
                const int row = row0 + wm + mt * 16 + rg + r;
                C[(size_t)row * OUT_DIM + col] = a[r] * oscale + bv;
            }
        }
    }
}

extern "C" void kernel_launch(void* const* d_in, const int* in_sizes, int n_in,
                              void* d_out, int out_size, void* d_ws, size_t ws_size,
                              hipStream_t stream) {
    const float* x    = (const float*)d_in[0];
    const float* wgt  = (const float*)d_in[1];
    const float* bias = (const float*)d_in[2];
    const int*   wsf  = (const int*)d_in[3];
    const int*   asf  = (const int*)d_in[4];

    bf16* tx = (bf16*)d_ws;
    bf16* tw = (bf16*)((char*)d_ws + (size_t)B_DIM * IN_DIM * sizeof(bf16));

    const int nx4 = B_DIM * IN_DIM / 4;     // 4,194,304
    const int nw4 = OUT_DIM * IN_DIM / 4;   // 65,536
    quant_kernel<<<(nx4 + 255) / 256, 256, 0, stream>>>(x, tx, nx4, asf);
    quant_kernel<<<(nw4 + 255) / 256, 256, 0, stream>>>(wgt, tw, nw4, wsf);

    const int grid = (B_DIM / 128) * (OUT_DIM / 128); // 1024
    gemm_bt<<<grid, 256, 0, stream>>>(tx, tw, bias, (float*)d_out, wsf, asf);
}